// Round 1
// baseline (776.126 us; speedup 1.0000x reference)
//
#include <hip/hip_runtime.h>
#include <math.h>

#define Bv 4
#define Tv 1024
#define Dv 1024
#define Hv 16
#define DHv 64

// ---------------- Kernel 1: QKV projection GEMMs ----------------
// C = x @ W + bias ; x: (4096,1024) row-major, W: (1024,1024) row-major.
// 128x128 tile, BK=8, 256 threads, 8x8 microtile. blockIdx.z picks Q/K/V.
__global__ __launch_bounds__(256) void qkv_gemm(
    const float* __restrict__ x,
    const float* __restrict__ Wq, const float* __restrict__ bq,
    const float* __restrict__ Wk, const float* __restrict__ bk,
    const float* __restrict__ Wv, const float* __restrict__ bv,
    float* __restrict__ Qo, float* __restrict__ Ko, float* __restrict__ Vo)
{
    const int N = Dv, K = Dv;
    const float* W; const float* bias; float* out;
    if (blockIdx.z == 0)      { W = Wq; bias = bq; out = Qo; }
    else if (blockIdx.z == 1) { W = Wk; bias = bk; out = Ko; }
    else                      { W = Wv; bias = bv; out = Vo; }

    __shared__ float As[8][128];   // As[k][m] (transposed on store)
    __shared__ float Bs[8][128];   // Bs[k][n]

    const int tid = threadIdx.x;
    const int tx = tid & 15, ty = tid >> 4;
    const int bm = blockIdx.y * 128, bn = blockIdx.x * 128;

    const int arow  = tid >> 1;        // 0..127
    const int acol  = (tid & 1) * 4;   // 0 or 4
    const int bkrow = tid >> 5;        // 0..7
    const int bcol  = (tid & 31) * 4;  // 0..124

    float acc[8][8];
#pragma unroll
    for (int i = 0; i < 8; i++)
#pragma unroll
        for (int j = 0; j < 8; j++) acc[i][j] = 0.f;

    for (int k0 = 0; k0 < K; k0 += 8) {
        __syncthreads();
        float4 av  = *reinterpret_cast<const float4*>(&x[(size_t)(bm + arow) * K + k0 + acol]);
        float4 bv4 = *reinterpret_cast<const float4*>(&W[(size_t)(k0 + bkrow) * N + bn + bcol]);
        As[acol + 0][arow] = av.x;
        As[acol + 1][arow] = av.y;
        As[acol + 2][arow] = av.z;
        As[acol + 3][arow] = av.w;
        *reinterpret_cast<float4*>(&Bs[bkrow][bcol]) = bv4;
        __syncthreads();
#pragma unroll
        for (int kk = 0; kk < 8; kk++) {
            float4 a0 = *reinterpret_cast<const float4*>(&As[kk][ty * 8]);
            float4 a1 = *reinterpret_cast<const float4*>(&As[kk][ty * 8 + 4]);
            float4 b0 = *reinterpret_cast<const float4*>(&Bs[kk][tx * 8]);
            float4 b1 = *reinterpret_cast<const float4*>(&Bs[kk][tx * 8 + 4]);
            float a[8] = {a0.x, a0.y, a0.z, a0.w, a1.x, a1.y, a1.z, a1.w};
            float b[8] = {b0.x, b0.y, b0.z, b0.w, b1.x, b1.y, b1.z, b1.w};
#pragma unroll
            for (int i = 0; i < 8; i++)
#pragma unroll
                for (int j = 0; j < 8; j++)
                    acc[i][j] = fmaf(a[i], b[j], acc[i][j]);
        }
    }
#pragma unroll
    for (int i = 0; i < 8; i++) {
        const int row = bm + ty * 8 + i;
#pragma unroll
        for (int j = 0; j < 8; j += 4) {
            const int col = bn + tx * 8 + j;
            float4 o;
            o.x = acc[i][j + 0] + bias[col + 0];
            o.y = acc[i][j + 1] + bias[col + 1];
            o.z = acc[i][j + 2] + bias[col + 2];
            o.w = acc[i][j + 3] + bias[col + 3];
            *reinterpret_cast<float4*>(&out[(size_t)row * N + col]) = o;
        }
    }
}

// ---------------- Kernel 2: logit row stats (m, 1/Z) ----------------
// Per (b, h, t-tile of 64): L[t,s] = sum_{j<64} K[r0+j, t0+t] * V[r0+j, s]
// online softmax over s in [0,1024). Writes m and 1/Z per (b,h,t).
__global__ __launch_bounds__(256) void attn_stats(
    const float* __restrict__ Kq, const float* __restrict__ Vq,
    const float* __restrict__ temp,
    float* __restrict__ mOut, float* __restrict__ zOut)
{
    const int b = blockIdx.z, h = blockIdx.y;
    const int t0 = blockIdx.x * 64;
    const int r0 = h * DHv;
    const float tscale = temp[h];

    __shared__ float Ks[64][68];   // Ks[j][tl]
    __shared__ float Vs[64][68];   // Vs[j][sl]
    __shared__ float redm[64][16];
    __shared__ float redz[64][16];

    const int tid = threadIdx.x;
    const int tx = tid & 15, ty = tid >> 4;
    const size_t base = (size_t)(b * Tv + r0) * Dv;

#pragma unroll
    for (int rep = 0; rep < 4; rep++) {
        const int idx = rep * 256 + tid;
        const int j = idx >> 4;
        const int c4 = (idx & 15) * 4;
        float4 v = *reinterpret_cast<const float4*>(&Kq[base + (size_t)j * Dv + t0 + c4]);
        *reinterpret_cast<float4*>(&Ks[j][c4]) = v;
    }

    float m_run[4], z_run[4];
#pragma unroll
    for (int i = 0; i < 4; i++) { m_run[i] = -INFINITY; z_run[i] = 0.f; }

    for (int s0 = 0; s0 < Dv; s0 += 64) {
        __syncthreads();
#pragma unroll
        for (int rep = 0; rep < 4; rep++) {
            const int idx = rep * 256 + tid;
            const int j = idx >> 4;
            const int c4 = (idx & 15) * 4;
            float4 v = *reinterpret_cast<const float4*>(&Vq[base + (size_t)j * Dv + s0 + c4]);
            *reinterpret_cast<float4*>(&Vs[j][c4]) = v;
        }
        __syncthreads();

        float l[4][4];
#pragma unroll
        for (int i = 0; i < 4; i++)
#pragma unroll
            for (int k = 0; k < 4; k++) l[i][k] = 0.f;

#pragma unroll 8
        for (int j = 0; j < 64; j++) {
            float4 a  = *reinterpret_cast<const float4*>(&Ks[j][ty * 4]);
            float4 vv = *reinterpret_cast<const float4*>(&Vs[j][tx * 4]);
            float af[4] = {a.x, a.y, a.z, a.w};
            float vf[4] = {vv.x, vv.y, vv.z, vv.w};
#pragma unroll
            for (int i = 0; i < 4; i++)
#pragma unroll
                for (int k = 0; k < 4; k++)
                    l[i][k] = fmaf(af[i], vf[k], l[i][k]);
        }

#pragma unroll
        for (int i = 0; i < 4; i++) {
#pragma unroll
            for (int k = 0; k < 4; k++) l[i][k] *= tscale;
            float mloc = fmaxf(fmaxf(l[i][0], l[i][1]), fmaxf(l[i][2], l[i][3]));
            float m_new = fmaxf(m_run[i], mloc);
            float zc = z_run[i] * __expf(m_run[i] - m_new);
            zc += __expf(l[i][0] - m_new);
            zc += __expf(l[i][1] - m_new);
            zc += __expf(l[i][2] - m_new);
            zc += __expf(l[i][3] - m_new);
            z_run[i] = zc;
            m_run[i] = m_new;
        }
    }

#pragma unroll
    for (int i = 0; i < 4; i++) {
        redm[ty * 4 + i][tx] = m_run[i];
        redz[ty * 4 + i][tx] = z_run[i];
    }
    __syncthreads();
    if (tid < 64) {
        float mf = -INFINITY;
#pragma unroll
        for (int q = 0; q < 16; q++) mf = fmaxf(mf, redm[tid][q]);
        float z = 0.f;
#pragma unroll
        for (int q = 0; q < 16; q++) z += redz[tid][q] * __expf(redm[tid][q] - mf);
        const int o = (b * Hv + h) * Tv + t0 + tid;
        mOut[o] = mf;
        zOut[o] = 1.f / z;
    }
}

// ---------------- Kernel 3: output ----------------
// Per (b, h, s-tile of 64): out[dh, s] = sum_t Q[r0+dh, t] * exp(L[t,s]*temp - m[t]) / Z[t]
__global__ __launch_bounds__(256) void attn_out(
    const float* __restrict__ Qq, const float* __restrict__ Kq, const float* __restrict__ Vq,
    const float* __restrict__ temp,
    const float* __restrict__ mIn, const float* __restrict__ zIn,
    float* __restrict__ out)
{
    const int b = blockIdx.z, h = blockIdx.y;
    const int s0 = blockIdx.x * 64;
    const int r0 = h * DHv;
    const float tscale = temp[h];

    __shared__ float Vs[64][68];   // Vs[j][sl]
    __shared__ float Ks[64][68];   // Ks[j][tl]
    __shared__ float Qs[64][68];   // Qs[tl][dh]  (transposed on store)
    __shared__ float Ps[64][68];   // Ps[tl][sl]
    __shared__ float ms[64];
    __shared__ float zs[64];

    const int tid = threadIdx.x;
    const int tx = tid & 15, ty = tid >> 4;
    const size_t base = (size_t)(b * Tv + r0) * Dv;

#pragma unroll
    for (int rep = 0; rep < 4; rep++) {
        const int idx = rep * 256 + tid;
        const int j = idx >> 4;
        const int c4 = (idx & 15) * 4;
        float4 v = *reinterpret_cast<const float4*>(&Vq[base + (size_t)j * Dv + s0 + c4]);
        *reinterpret_cast<float4*>(&Vs[j][c4]) = v;
    }

    float acc[4][4];
#pragma unroll
    for (int i = 0; i < 4; i++)
#pragma unroll
        for (int k = 0; k < 4; k++) acc[i][k] = 0.f;

    for (int t0 = 0; t0 < Tv; t0 += 64) {
        __syncthreads();
#pragma unroll
        for (int rep = 0; rep < 4; rep++) {
            const int idx = rep * 256 + tid;
            const int j = idx >> 4;        // row (j for K, dh for Q)
            const int c4 = (idx & 15) * 4; // col within tile
            float4 kv = *reinterpret_cast<const float4*>(&Kq[base + (size_t)j * Dv + t0 + c4]);
            *reinterpret_cast<float4*>(&Ks[j][c4]) = kv;
            float4 qv = *reinterpret_cast<const float4*>(&Qq[base + (size_t)j * Dv + t0 + c4]);
            Qs[c4 + 0][j] = qv.x;
            Qs[c4 + 1][j] = qv.y;
            Qs[c4 + 2][j] = qv.z;
            Qs[c4 + 3][j] = qv.w;
        }
        if (tid < 64) {
            const int o = (b * Hv + h) * Tv + t0 + tid;
            ms[tid] = mIn[o];
            zs[tid] = zIn[o];
        }
        __syncthreads();

        // L tile: rows tl = ty*4+i, cols sl = tx*4+k
        float l[4][4];
#pragma unroll
        for (int i = 0; i < 4; i++)
#pragma unroll
            for (int k = 0; k < 4; k++) l[i][k] = 0.f;

#pragma unroll 8
        for (int j = 0; j < 64; j++) {
            float4 a  = *reinterpret_cast<const float4*>(&Ks[j][ty * 4]);
            float4 vv = *reinterpret_cast<const float4*>(&Vs[j][tx * 4]);
            float af[4] = {a.x, a.y, a.z, a.w};
            float vf[4] = {vv.x, vv.y, vv.z, vv.w};
#pragma unroll
            for (int i = 0; i < 4; i++)
#pragma unroll
                for (int k = 0; k < 4; k++)
                    l[i][k] = fmaf(af[i], vf[k], l[i][k]);
        }

#pragma unroll
        for (int i = 0; i < 4; i++) {
            const float mi = ms[ty * 4 + i];
            const float zi = zs[ty * 4 + i];
            float4 p;
            p.x = __expf(l[i][0] * tscale - mi) * zi;
            p.y = __expf(l[i][1] * tscale - mi) * zi;
            p.z = __expf(l[i][2] * tscale - mi) * zi;
            p.w = __expf(l[i][3] * tscale - mi) * zi;
            *reinterpret_cast<float4*>(&Ps[ty * 4 + i][tx * 4]) = p;
        }
        __syncthreads();

        // acc[dh, sl] += Q[dh, tl] * P[tl, sl]; rows dh = ty*4+i
#pragma unroll 8
        for (int tl = 0; tl < 64; tl++) {
            float4 q = *reinterpret_cast<const float4*>(&Qs[tl][ty * 4]);
            float4 p = *reinterpret_cast<const float4*>(&Ps[tl][tx * 4]);
            float qf[4] = {q.x, q.y, q.z, q.w};
            float pf[4] = {p.x, p.y, p.z, p.w};
#pragma unroll
            for (int i = 0; i < 4; i++)
#pragma unroll
                for (int k = 0; k < 4; k++)
                    acc[i][k] = fmaf(qf[i], pf[k], acc[i][k]);
        }
    }

#pragma unroll
    for (int i = 0; i < 4; i++) {
        float4 o;
        o.x = acc[i][0];
        o.y = acc[i][1];
        o.z = acc[i][2];
        o.w = acc[i][3];
        *reinterpret_cast<float4*>(&out[base + (size_t)(ty * 4 + i) * Dv + s0 + tx * 4]) = o;
    }
}

extern "C" void kernel_launch(void* const* d_in, const int* in_sizes, int n_in,
                              void* d_out, int out_size, void* d_ws, size_t ws_size,
                              hipStream_t stream) {
    const float* x    = (const float*)d_in[0];
    const float* Wq   = (const float*)d_in[1];
    const float* bq   = (const float*)d_in[2];
    const float* Wk   = (const float*)d_in[3];
    const float* bk   = (const float*)d_in[4];
    const float* Wv   = (const float*)d_in[5];
    const float* bv   = (const float*)d_in[6];
    const float* temp = (const float*)d_in[7];
    float* out = (float*)d_out;

    float* ws = (float*)d_ws;
    float* Q    = ws;                  // 4M floats
    float* K    = ws + 4194304;        // 4M floats
    float* V    = ws + 8388608;        // 4M floats
    float* mbuf = ws + 12582912;       // 65536 floats
    float* zbuf = mbuf + 65536;        // 65536 floats

    qkv_gemm<<<dim3(Dv / 128, (Bv * Tv) / 128, 3), 256, 0, stream>>>(
        x, Wq, bq, Wk, bk, Wv, bv, Q, K, V);
    attn_stats<<<dim3(Tv / 64, Hv, Bv), 256, 0, stream>>>(K, V, temp, mbuf, zbuf);
    attn_out<<<dim3(Dv / 64, Hv, Bv), 256, 0, stream>>>(Q, K, V, temp, mbuf, zbuf, out);
}

// Round 2
// 202.543 us; speedup vs baseline: 3.8319x; 3.8319x over previous
//
#include <hip/hip_runtime.h>
#include <math.h>

#define Bv 4
#define Tv 1024
#define Dv 1024
#define Hv 16
#define DHv 64

typedef __attribute__((ext_vector_type(8))) short short8;
typedef __attribute__((ext_vector_type(4))) short short4v;
typedef __attribute__((ext_vector_type(4))) float f32x4;

#define MFMA16(a, b, c) __builtin_amdgcn_mfma_f32_16x16x32_bf16((a), (b), (c), 0, 0, 0)

__device__ __forceinline__ short f2bf(float f) {
    union { float f; unsigned u; } v; v.f = f;
    unsigned r = v.u + 0x7FFFu + ((v.u >> 16) & 1u);
    return (short)(r >> 16);
}

__device__ __forceinline__ void async16(const void* g, void* l) {
    __builtin_amdgcn_global_load_lds(
        (const __attribute__((address_space(1))) void*)g,
        (__attribute__((address_space(3))) void*)l, 16, 0, 0);
}

// Fragment read from a 64-short-wide tile stored with chunk-XOR swizzle
// (chunk cw of row r lives at slot cw ^ (r&7)). 2-way bank aliasing only.
__device__ __forceinline__ short8 frag64(const short* buf, int r, int cw) {
    return *(const short8*)&buf[r * 64 + ((cw ^ (r & 7)) << 3)];
}

// ---------------- cast x -> bf16 ----------------
__global__ __launch_bounds__(256) void cast_x(const float* __restrict__ x, short* __restrict__ xb) {
    const int idx = blockIdx.x * 256 + threadIdx.x;     // 1M threads x 4 elems
    float4 v = ((const float4*)x)[idx];
    short4v o;
    o[0] = f2bf(v.x); o[1] = f2bf(v.y); o[2] = f2bf(v.z); o[3] = f2bf(v.w);
    ((short4v*)xb)[idx] = o;
}

// ---------------- cast + transpose W -> Wt[n][k] bf16 ----------------
__global__ __launch_bounds__(256) void w_cast_t(
    const float* __restrict__ Wq, const float* __restrict__ Wk, const float* __restrict__ Wv,
    short* __restrict__ Wt)
{
    const float* W = (blockIdx.z == 0) ? Wq : (blockIdx.z == 1) ? Wk : Wv;
    short* Wto = Wt + (size_t)blockIdx.z * 1048576;
    __shared__ short Tl[64 * 72];
    const int k0 = blockIdx.y * 64, n0 = blockIdx.x * 64;
    const int tid = threadIdx.x;
    {
        const int r = tid >> 2, c16 = (tid & 3) * 16;
        const float* src = W + (size_t)(k0 + r) * Dv + n0 + c16;
        float4 f0 = ((const float4*)src)[0], f1 = ((const float4*)src)[1];
        float4 f2 = ((const float4*)src)[2], f3 = ((const float4*)src)[3];
        short8 s0, s1;
        s0[0] = f2bf(f0.x); s0[1] = f2bf(f0.y); s0[2] = f2bf(f0.z); s0[3] = f2bf(f0.w);
        s0[4] = f2bf(f1.x); s0[5] = f2bf(f1.y); s0[6] = f2bf(f1.z); s0[7] = f2bf(f1.w);
        s1[0] = f2bf(f2.x); s1[1] = f2bf(f2.y); s1[2] = f2bf(f2.z); s1[3] = f2bf(f2.w);
        s1[4] = f2bf(f3.x); s1[5] = f2bf(f3.y); s1[6] = f2bf(f3.z); s1[7] = f2bf(f3.w);
        *(short8*)&Tl[r * 72 + c16] = s0;
        *(short8*)&Tl[r * 72 + c16 + 8] = s1;
    }
    __syncthreads();
#pragma unroll
    for (int p = 0; p < 2; p++) {
        const int n = p * 32 + (tid >> 3), j8 = (tid & 7) * 8;
        short8 o;
#pragma unroll
        for (int jj = 0; jj < 8; jj++) o[jj] = Tl[(j8 + jj) * 72 + n];
        *(short8*)&Wto[(size_t)(n0 + n) * Dv + k0 + j8] = o;
    }
}

// ---------------- QKV projection: bf16 MFMA GEMM ----------------
// C[m][n] = sum_k xb[m][k] * Wt[n][k] + bias[n], out bf16 natural layout.
__global__ __launch_bounds__(256) void qkv_mfma(
    const short* __restrict__ xb, const short* __restrict__ Wt3,
    const float* __restrict__ bq, const float* __restrict__ bk, const float* __restrict__ bv,
    short* __restrict__ Qo, short* __restrict__ Ko, short* __restrict__ Vo)
{
    const short* Wt = Wt3 + (size_t)blockIdx.z * 1048576;
    const float* bias = (blockIdx.z == 0) ? bq : (blockIdx.z == 1) ? bk : bv;
    short* out = (blockIdx.z == 0) ? Qo : (blockIdx.z == 1) ? Ko : Vo;

    __shared__ short As[128 * 64];
    __shared__ short Bs[128 * 64];

    const int tid = threadIdx.x;
    const int lane = tid & 63, w = tid >> 6;
    const int q = lane >> 4, c = lane & 15;
    const int wm = (w >> 1) * 64, wn = (w & 1) * 64;
    const int bm = blockIdx.y * 128, bn = blockIdx.x * 128;

    f32x4 acc[4][4] = {};

    for (int k0 = 0; k0 < Dv; k0 += 64) {
#pragma unroll
        for (int p = 0; p < 4; p++) {
            const int idx = p * 256 + tid;
            const int r = idx >> 3, cs = idx & 7, cg = cs ^ (r & 7);
            async16(xb + (size_t)(bm + r) * Dv + k0 + cg * 8, As + idx * 8);
            async16(Wt + (size_t)(bn + r) * Dv + k0 + cg * 8, Bs + idx * 8);
        }
        __syncthreads();
#pragma unroll
        for (int kk = 0; kk < 2; kk++) {
            short8 af[4], bf[4];
#pragma unroll
            for (int i = 0; i < 4; i++) {
                af[i] = frag64(As, wm + i * 16 + c, kk * 4 + q);
                bf[i] = frag64(Bs, wn + i * 16 + c, kk * 4 + q);
            }
#pragma unroll
            for (int i = 0; i < 4; i++)
#pragma unroll
                for (int j = 0; j < 4; j++)
                    acc[i][j] = MFMA16(af[i], bf[j], acc[i][j]);
        }
        __syncthreads();
    }

#pragma unroll
    for (int j = 0; j < 4; j++) {
        const int col = bn + wn + j * 16 + c;
        const float bb = bias[col];
#pragma unroll
        for (int i = 0; i < 4; i++) {
#pragma unroll
            for (int r = 0; r < 4; r++) {
                const int row = bm + wm + i * 16 + q * 4 + r;
                out[(size_t)row * Dv + col] = f2bf(acc[i][j][r] + bb);
            }
        }
    }
}

// ---------------- transpose K,V per head: Kt[(b,h)][t][j] ----------------
__global__ __launch_bounds__(256) void kv_transpose(
    const short* __restrict__ Kb, const short* __restrict__ Vb,
    short* __restrict__ Kt, short* __restrict__ Vt)
{
    const short* src = blockIdx.z ? Vb : Kb;
    short* dst = blockIdx.z ? Vt : Kt;
    const int bh = blockIdx.y;
    const int b = bh >> 4, h = bh & 15;
    const int t0 = blockIdx.x * 64;
    __shared__ short Tl[64 * 72];
    const int tid = threadIdx.x;
    const size_t base = (size_t)(b * Tv + h * DHv) * Dv;
#pragma unroll
    for (int p = 0; p < 2; p++) {
        const int idx = p * 256 + tid;
        const int j = idx >> 3, c8 = (idx & 7) * 8;
        short8 v = *(const short8*)&src[base + (size_t)j * Dv + t0 + c8];
        *(short8*)&Tl[j * 72 + c8] = v;
    }
    __syncthreads();
#pragma unroll
    for (int p = 0; p < 2; p++) {
        const int t = p * 32 + (tid >> 3), j8 = (tid & 7) * 8;
        short8 o;
#pragma unroll
        for (int jj = 0; jj < 8; jj++) o[jj] = Tl[(j8 + jj) * 72 + t];
        *(short8*)&dst[(size_t)bh * 65536 + (size_t)(t0 + t) * 64 + j8] = o;
    }
}

// ---------------- attention stats: row max m, 1/Z per (b,h,t) ----------------
__global__ __launch_bounds__(256) void attn_stats(
    const short* __restrict__ Kt, const short* __restrict__ Vt,
    const float* __restrict__ temp,
    float* __restrict__ mOut, float* __restrict__ zOut)
{
    const int b = blockIdx.z, h = blockIdx.y, t0 = blockIdx.x * 64;
    const int bh = b * Hv + h;
    const float ts = temp[h];
    __shared__ short Ks[64 * 64];
    __shared__ short Vs[64 * 64];
    const int tid = threadIdx.x;
    const int lane = tid & 63, w = tid >> 6;
    const int q = lane >> 4, c = lane & 15;
    const short* Kbase = Kt + (size_t)bh * 65536;
    const short* Vbase = Vt + (size_t)bh * 65536;

#pragma unroll
    for (int p = 0; p < 2; p++) {
        const int idx = p * 256 + tid;
        const int r = idx >> 3, cs = idx & 7, cg = cs ^ (r & 7);
        async16(Kbase + (size_t)(t0 + r) * 64 + cg * 8, Ks + idx * 8);
    }

    float m_run[4], z_run[4];
#pragma unroll
    for (int r = 0; r < 4; r++) { m_run[r] = -INFINITY; z_run[r] = 0.f; }

    short8 aK0, aK1;
    for (int s0 = 0; s0 < Tv; s0 += 64) {
        __syncthreads();
#pragma unroll
        for (int p = 0; p < 2; p++) {
            const int idx = p * 256 + tid;
            const int r = idx >> 3, cs = idx & 7, cg = cs ^ (r & 7);
            async16(Vbase + (size_t)(s0 + r) * 64 + cg * 8, Vs + idx * 8);
        }
        __syncthreads();
        if (s0 == 0) {
            aK0 = frag64(Ks, w * 16 + c, q);
            aK1 = frag64(Ks, w * 16 + c, 4 + q);
        }
        float lv[4][4];
#pragma unroll
        for (int sf = 0; sf < 4; sf++) {
            short8 b0 = frag64(Vs, sf * 16 + c, q);
            short8 b1 = frag64(Vs, sf * 16 + c, 4 + q);
            f32x4 l = {0.f, 0.f, 0.f, 0.f};
            l = MFMA16(aK0, b0, l);
            l = MFMA16(aK1, b1, l);
#pragma unroll
            for (int r = 0; r < 4; r++) lv[sf][r] = l[r] * ts;
        }
#pragma unroll
        for (int r = 0; r < 4; r++) {
            float vmax = fmaxf(fmaxf(lv[0][r], lv[1][r]), fmaxf(lv[2][r], lv[3][r]));
            float mn = fmaxf(m_run[r], vmax);
            float za = __expf(lv[0][r] - mn) + __expf(lv[1][r] - mn) +
                       __expf(lv[2][r] - mn) + __expf(lv[3][r] - mn);
            z_run[r] = z_run[r] * __expf(m_run[r] - mn) + za;
            m_run[r] = mn;
        }
    }
    // reduce (m,z) across the 16 column-lanes of each quad
#pragma unroll
    for (int mask = 1; mask <= 8; mask <<= 1) {
#pragma unroll
        for (int r = 0; r < 4; r++) {
            float om = __shfl_xor(m_run[r], mask, 64);
            float oz = __shfl_xor(z_run[r], mask, 64);
            float mn = fmaxf(m_run[r], om);
            z_run[r] = z_run[r] * __expf(m_run[r] - mn) + oz * __expf(om - mn);
            m_run[r] = mn;
        }
    }
    if (c == 0) {
#pragma unroll
        for (int r = 0; r < 4; r++) {
            const int t = t0 + w * 16 + q * 4 + r;
            mOut[(size_t)bh * Tv + t] = m_run[r];
            zOut[(size_t)bh * Tv + t] = 1.f / z_run[r];
        }
    }
}

// ---------------- attention output ----------------
__global__ __launch_bounds__(256) void attn_out(
    const short* __restrict__ Qb, const short* __restrict__ Kt, const short* __restrict__ Vt,
    const float* __restrict__ temp, const float* __restrict__ mIn, const float* __restrict__ zIn,
    float* __restrict__ out)
{
    const int b = blockIdx.z, h = blockIdx.y, s0 = blockIdx.x * 64;
    const int bh = b * Hv + h;
    const float ts = temp[h];
    __shared__ short Vs[64 * 64];
    __shared__ short Ks[64 * 64];
    __shared__ short Qs[64 * 64];
    __shared__ short Pt[64 * 72];
    __shared__ float ms[64], zs[64];
    const int tid = threadIdx.x;
    const int lane = tid & 63, w = tid >> 6;
    const int q = lane >> 4, c = lane & 15;
    const short* Vbase = Vt + (size_t)bh * 65536;
    const short* Kbase = Kt + (size_t)bh * 65536;
    const short* Qbase = Qb + (size_t)(b * Tv + h * DHv) * Dv;

#pragma unroll
    for (int p = 0; p < 2; p++) {
        const int idx = p * 256 + tid;
        const int r = idx >> 3, cs = idx & 7, cg = cs ^ (r & 7);
        async16(Vbase + (size_t)(s0 + r) * 64 + cg * 8, Vs + idx * 8);
    }

    f32x4 acc[4] = {};

    for (int t0 = 0; t0 < Tv; t0 += 64) {
        __syncthreads();
#pragma unroll
        for (int p = 0; p < 2; p++) {
            const int idx = p * 256 + tid;
            const int r = idx >> 3, cs = idx & 7, cg = cs ^ (r & 7);
            async16(Kbase + (size_t)(t0 + r) * 64 + cg * 8, Ks + idx * 8);
            async16(Qbase + (size_t)r * Dv + t0 + cg * 8, Qs + idx * 8);
        }
        if (tid < 64) {
            ms[tid] = mIn[(size_t)bh * Tv + t0 + tid];
            zs[tid] = zIn[(size_t)bh * Tv + t0 + tid];
        }
        __syncthreads();

        short8 aK0 = frag64(Ks, w * 16 + c, q);
        short8 aK1 = frag64(Ks, w * 16 + c, 4 + q);
#pragma unroll
        for (int sf = 0; sf < 4; sf++) {
            short8 b0 = frag64(Vs, sf * 16 + c, q);
            short8 b1 = frag64(Vs, sf * 16 + c, 4 + q);
            f32x4 l = {0.f, 0.f, 0.f, 0.f};
            l = MFMA16(aK0, b0, l);
            l = MFMA16(aK1, b1, l);
            short4v p4;
#pragma unroll
            for (int r = 0; r < 4; r++) {
                const int tr = w * 16 + q * 4 + r;
                float p = __expf(l[r] * ts - ms[tr]) * zs[tr];
                p4[r] = f2bf(p);
            }
            *(short4v*)&Pt[(sf * 16 + c) * 72 + w * 16 + q * 4] = p4;
        }
        __syncthreads();

        short8 aQ0 = frag64(Qs, w * 16 + c, q);
        short8 aQ1 = frag64(Qs, w * 16 + c, 4 + q);
#pragma unroll
        for (int sf = 0; sf < 4; sf++) {
            short8 p0 = *(const short8*)&Pt[(sf * 16 + c) * 72 + q * 8];
            short8 p1 = *(const short8*)&Pt[(sf * 16 + c) * 72 + 32 + q * 8];
            acc[sf] = MFMA16(aQ0, p0, acc[sf]);
            acc[sf] = MFMA16(aQ1, p1, acc[sf]);
        }
    }

#pragma unroll
    for (int sf = 0; sf < 4; sf++) {
#pragma unroll
        for (int r = 0; r < 4; r++) {
            const int d = w * 16 + q * 4 + r;
            out[(size_t)(b * Tv + h * DHv + d) * Dv + s0 + sf * 16 + c] = acc[sf][r];
        }
    }
}

extern "C" void kernel_launch(void* const* d_in, const int* in_sizes, int n_in,
                              void* d_out, int out_size, void* d_ws, size_t ws_size,
                              hipStream_t stream) {
    const float* x    = (const float*)d_in[0];
    const float* Wq   = (const float*)d_in[1];
    const float* bq   = (const float*)d_in[2];
    const float* Wk   = (const float*)d_in[3];
    const float* bk   = (const float*)d_in[4];
    const float* Wv   = (const float*)d_in[5];
    const float* bv   = (const float*)d_in[6];
    const float* temp = (const float*)d_in[7];
    float* out = (float*)d_out;

    char* ws = (char*)d_ws;
    short* xb = (short*)(ws);                       // [0, 8M)
    short* Wt = (short*)(ws + ((size_t)8 << 20));   // [8M, 14M)
    short* Kt = (short*)(ws);                       // alias xb (dead after qkv_mfma)
    short* Vt = (short*)(ws + ((size_t)8 << 20));   // alias Wt + 2MB slack: [8M, 16M)
    short* Kb = (short*)(ws + ((size_t)16 << 20));  // [16M, 24M)
    short* Vb = (short*)(ws + ((size_t)24 << 20));  // [24M, 32M)
    short* Qb = (short*)(ws + ((size_t)32 << 20));  // [32M, 40M)
    float* mbuf = (float*)(ws + ((size_t)40 << 20));
    float* zbuf = mbuf + 65536;

    cast_x<<<4096, 256, 0, stream>>>(x, xb);
    w_cast_t<<<dim3(16, 16, 3), 256, 0, stream>>>(Wq, Wk, Wv, Wt);
    qkv_mfma<<<dim3(8, 32, 3), 256, 0, stream>>>(xb, Wt, bq, bk, bv, Qb, Kb, Vb);
    kv_transpose<<<dim3(16, 64, 2), 256, 0, stream>>>(Kb, Vb, Kt, Vt);
    attn_stats<<<dim3(16, 16, 4), 256, 0, stream>>>(Kt, Vt, temp, mbuf, zbuf);
    attn_out<<<dim3(16, 16, 4), 256, 0, stream>>>(Qb, Kt, Vt, temp, mbuf, zbuf, out);
}

// Round 3
// 197.090 us; speedup vs baseline: 3.9379x; 1.0277x over previous
//
#include <hip/hip_runtime.h>
#include <math.h>

#define Bv 4
#define Tv 1024
#define Dv 1024
#define Hv 16
#define DHv 64

typedef __attribute__((ext_vector_type(8))) short short8;
typedef __attribute__((ext_vector_type(4))) short short4v;
typedef __attribute__((ext_vector_type(4))) float f32x4;

#define MFMA16(a, b, c) __builtin_amdgcn_mfma_f32_16x16x32_bf16((a), (b), (c), 0, 0, 0)

__device__ __forceinline__ short f2bf(float f) {
    union { float f; unsigned u; } v; v.f = f;
    unsigned r = v.u + 0x7FFFu + ((v.u >> 16) & 1u);
    return (short)(r >> 16);
}

__device__ __forceinline__ void async16(const void* g, void* l) {
    __builtin_amdgcn_global_load_lds(
        (const __attribute__((address_space(1))) void*)g,
        (__attribute__((address_space(3))) void*)l, 16, 0, 0);
}

// Fragment read from a 64-short-wide tile stored with chunk-XOR swizzle
// (chunk cw of row r lives at slot cw ^ (r&7)). 2-way bank aliasing only.
__device__ __forceinline__ short8 frag64(const short* buf, int r, int cw) {
    return *(const short8*)&buf[r * 64 + ((cw ^ (r & 7)) << 3)];
}

// ---------------- cast x -> bf16 ----------------
__global__ __launch_bounds__(256) void cast_x(const float* __restrict__ x, short* __restrict__ xb) {
    const int idx = blockIdx.x * 256 + threadIdx.x;
    float4 v = ((const float4*)x)[idx];
    short4v o;
    o[0] = f2bf(v.x); o[1] = f2bf(v.y); o[2] = f2bf(v.z); o[3] = f2bf(v.w);
    ((short4v*)xb)[idx] = o;
}

// ---------------- cast + transpose W -> Wt[n][k] bf16 ----------------
__global__ __launch_bounds__(256) void w_cast_t(
    const float* __restrict__ Wq, const float* __restrict__ Wk, const float* __restrict__ Wv,
    short* __restrict__ Wt)
{
    const float* W = (blockIdx.z == 0) ? Wq : (blockIdx.z == 1) ? Wk : Wv;
    short* Wto = Wt + (size_t)blockIdx.z * 1048576;
    __shared__ short Tl[64 * 72];
    const int k0 = blockIdx.y * 64, n0 = blockIdx.x * 64;
    const int tid = threadIdx.x;
    {
        const int r = tid >> 2, c16 = (tid & 3) * 16;
        const float* src = W + (size_t)(k0 + r) * Dv + n0 + c16;
        float4 f0 = ((const float4*)src)[0], f1 = ((const float4*)src)[1];
        float4 f2 = ((const float4*)src)[2], f3 = ((const float4*)src)[3];
        short8 s0, s1;
        s0[0] = f2bf(f0.x); s0[1] = f2bf(f0.y); s0[2] = f2bf(f0.z); s0[3] = f2bf(f0.w);
        s0[4] = f2bf(f1.x); s0[5] = f2bf(f1.y); s0[6] = f2bf(f1.z); s0[7] = f2bf(f1.w);
        s1[0] = f2bf(f2.x); s1[1] = f2bf(f2.y); s1[2] = f2bf(f2.z); s1[3] = f2bf(f2.w);
        s1[4] = f2bf(f3.x); s1[5] = f2bf(f3.y); s1[6] = f2bf(f3.z); s1[7] = f2bf(f3.w);
        *(short8*)&Tl[r * 72 + c16] = s0;
        *(short8*)&Tl[r * 72 + c16 + 8] = s1;
    }
    __syncthreads();
#pragma unroll
    for (int p = 0; p < 2; p++) {
        const int n = p * 32 + (tid >> 3), j8 = (tid & 7) * 8;
        short8 o;
#pragma unroll
        for (int jj = 0; jj < 8; jj++) o[jj] = Tl[(j8 + jj) * 72 + n];
        *(short8*)&Wto[(size_t)(n0 + n) * Dv + k0 + j8] = o;
    }
}

// ---------------- QKV projection: bf16 MFMA GEMM ----------------
// z=0: Q, natural layout out[token][feature].
// z=1,2: K,V written directly per-head transposed: dst[(b*16+h)][feature][tok&63].
__global__ __launch_bounds__(256) void qkv_mfma(
    const short* __restrict__ xb, const short* __restrict__ Wt3,
    const float* __restrict__ bq, const float* __restrict__ bk, const float* __restrict__ bv,
    short* __restrict__ Qo, short* __restrict__ Kt, short* __restrict__ Vt)
{
    const int z = blockIdx.z;
    const short* Wt = Wt3 + (size_t)z * 1048576;
    const float* bias = (z == 0) ? bq : (z == 1) ? bk : bv;

    __shared__ short smem[16896];          // As(8192) + Bs(8192); reused as T[128][132]
    short* As = smem;
    short* Bs = smem + 8192;

    const int tid = threadIdx.x;
    const int lane = tid & 63, w = tid >> 6;
    const int q = lane >> 4, c = lane & 15;
    const int wm = (w >> 1) * 64, wn = (w & 1) * 64;
    const int bm = blockIdx.y * 128, bn = blockIdx.x * 128;

    f32x4 acc[4][4] = {};

    for (int k0 = 0; k0 < Dv; k0 += 64) {
#pragma unroll
        for (int p = 0; p < 4; p++) {
            const int idx = p * 256 + tid;
            const int r = idx >> 3, cs = idx & 7, cg = cs ^ (r & 7);
            async16(xb + (size_t)(bm + r) * Dv + k0 + cg * 8, As + idx * 8);
            async16(Wt + (size_t)(bn + r) * Dv + k0 + cg * 8, Bs + idx * 8);
        }
        __syncthreads();
#pragma unroll
        for (int kk = 0; kk < 2; kk++) {
            short8 af[4], bf[4];
#pragma unroll
            for (int i = 0; i < 4; i++) {
                af[i] = frag64(As, wm + i * 16 + c, kk * 4 + q);
                bf[i] = frag64(Bs, wn + i * 16 + c, kk * 4 + q);
            }
#pragma unroll
            for (int i = 0; i < 4; i++)
#pragma unroll
                for (int j = 0; j < 4; j++)
                    acc[i][j] = MFMA16(af[i], bf[j], acc[i][j]);
        }
        __syncthreads();
    }

    if (z == 0) {
#pragma unroll
        for (int j = 0; j < 4; j++) {
            const int col = bn + wn + j * 16 + c;
            const float bb = bias[col];
#pragma unroll
            for (int i = 0; i < 4; i++) {
#pragma unroll
                for (int r = 0; r < 4; r++) {
                    const int row = bm + wm + i * 16 + q * 4 + r;
                    Qo[(size_t)row * Dv + col] = f2bf(acc[i][j][r] + bb);
                }
            }
        }
    } else {
        short* dst = (z == 1) ? Kt : Vt;
        short* T = smem;                   // T[n][m], stride 132, n,m in [0,128)
#pragma unroll
        for (int j = 0; j < 4; j++) {
            const int n = wn + j * 16 + c;
            const float bb = bias[bn + n];
#pragma unroll
            for (int i = 0; i < 4; i++) {
                short4v pk;
#pragma unroll
                for (int r = 0; r < 4; r++) pk[r] = f2bf(acc[i][j][r] + bb);
                *(short4v*)&T[n * 132 + wm + i * 16 + q * 4] = pk;
            }
        }
        __syncthreads();
        const int hb = bm >> 6;            // first head-block covered by this tile
#pragma unroll
        for (int p = 0; p < 8; p++) {
            const int idx = p * 256 + tid;
            const int n = idx >> 4, k2 = idx & 15;
            short8 v = *(const short8*)&T[n * 132 + k2 * 8];
            const size_t addr = (size_t)(hb + (k2 >> 3)) * 65536 +
                                (size_t)(bn + n) * 64 + (k2 & 7) * 8;
            *(short8*)&dst[addr] = v;
        }
    }
}

// ---------------- attention stats: row max m, 1/Z per (b,h,t) ----------------
__global__ __launch_bounds__(256) void attn_stats(
    const short* __restrict__ Kt, const short* __restrict__ Vt,
    const float* __restrict__ temp,
    float* __restrict__ mOut, float* __restrict__ zOut)
{
    const int b = blockIdx.z, h = blockIdx.y, t0 = blockIdx.x * 64;
    const int bh = b * Hv + h;
    const float ts = temp[h];
    __shared__ short Ks[64 * 64];
    __shared__ short Vs[128 * 64];
    const int tid = threadIdx.x;
    const int lane = tid & 63, w = tid >> 6;
    const int q = lane >> 4, c = lane & 15;
    const short* Kbase = Kt + (size_t)bh * 65536;
    const short* Vbase = Vt + (size_t)bh * 65536;

#pragma unroll
    for (int p = 0; p < 2; p++) {
        const int idx = p * 256 + tid;
        const int r = idx >> 3, cs = idx & 7, cg = cs ^ (r & 7);
        async16(Kbase + (size_t)(t0 + r) * 64 + cg * 8, Ks + idx * 8);
    }

    float m_run[4], z_run[4];
#pragma unroll
    for (int r = 0; r < 4; r++) { m_run[r] = -INFINITY; z_run[r] = 0.f; }

    short8 aK0, aK1;
    for (int s0 = 0; s0 < Tv; s0 += 128) {
        __syncthreads();
#pragma unroll
        for (int p = 0; p < 4; p++) {
            const int idx = p * 256 + tid;
            const int r = idx >> 3, cs = idx & 7, cg = cs ^ (r & 7);
            async16(Vbase + (size_t)(s0 + r) * 64 + cg * 8, Vs + idx * 8);
        }
        __syncthreads();
        if (s0 == 0) {
            aK0 = frag64(Ks, w * 16 + c, q);
            aK1 = frag64(Ks, w * 16 + c, 4 + q);
        }
        float lv[8][4];
#pragma unroll
        for (int sf = 0; sf < 8; sf++) {
            short8 b0 = frag64(Vs, sf * 16 + c, q);
            short8 b1 = frag64(Vs, sf * 16 + c, 4 + q);
            f32x4 l = {0.f, 0.f, 0.f, 0.f};
            l = MFMA16(aK0, b0, l);
            l = MFMA16(aK1, b1, l);
#pragma unroll
            for (int r = 0; r < 4; r++) lv[sf][r] = l[r] * ts;
        }
#pragma unroll
        for (int r = 0; r < 4; r++) {
            float vmax = lv[0][r];
#pragma unroll
            for (int sf = 1; sf < 8; sf++) vmax = fmaxf(vmax, lv[sf][r]);
            float mn = fmaxf(m_run[r], vmax);
            float za = 0.f;
#pragma unroll
            for (int sf = 0; sf < 8; sf++) za += __expf(lv[sf][r] - mn);
            z_run[r] = z_run[r] * __expf(m_run[r] - mn) + za;
            m_run[r] = mn;
        }
    }
#pragma unroll
    for (int mask = 1; mask <= 8; mask <<= 1) {
#pragma unroll
        for (int r = 0; r < 4; r++) {
            float om = __shfl_xor(m_run[r], mask, 64);
            float oz = __shfl_xor(z_run[r], mask, 64);
            float mn = fmaxf(m_run[r], om);
            z_run[r] = z_run[r] * __expf(m_run[r] - mn) + oz * __expf(om - mn);
            m_run[r] = mn;
        }
    }
    if (c == 0) {
#pragma unroll
        for (int r = 0; r < 4; r++) {
            const int t = t0 + w * 16 + q * 4 + r;
            mOut[(size_t)bh * Tv + t] = m_run[r];
            zOut[(size_t)bh * Tv + t] = 1.f / z_run[r];
        }
    }
}

// ---------------- attention output (s-tile = 128) ----------------
__global__ __launch_bounds__(256) void attn_out(
    const short* __restrict__ Qb, const short* __restrict__ Kt, const short* __restrict__ Vt,
    const float* __restrict__ temp, const float* __restrict__ mIn, const float* __restrict__ zIn,
    float* __restrict__ out)
{
    const int b = blockIdx.z, h = blockIdx.y, s0 = blockIdx.x * 128;
    const int bh = b * Hv + h;
    const float ts = temp[h];
    __shared__ short Vs[128 * 64];   // [s][j]
    __shared__ short Ks[64 * 64];    // [t][j]
    __shared__ short Qs[64 * 64];    // [dh][t]
    __shared__ short Pt[128 * 72];   // [s][t]
    __shared__ float ms[64], zs[64];
    const int tid = threadIdx.x;
    const int lane = tid & 63, w = tid >> 6;
    const int q = lane >> 4, c = lane & 15;
    const short* Vbase = Vt + (size_t)bh * 65536;
    const short* Kbase = Kt + (size_t)bh * 65536;
    const short* Qbase = Qb + (size_t)(b * Tv + h * DHv) * Dv;

#pragma unroll
    for (int p = 0; p < 4; p++) {
        const int idx = p * 256 + tid;
        const int r = idx >> 3, cs = idx & 7, cg = cs ^ (r & 7);
        async16(Vbase + (size_t)(s0 + r) * 64 + cg * 8, Vs + idx * 8);
    }

    f32x4 acc[8] = {};

    for (int t0 = 0; t0 < Tv; t0 += 64) {
        __syncthreads();
#pragma unroll
        for (int p = 0; p < 2; p++) {
            const int idx = p * 256 + tid;
            const int r = idx >> 3, cs = idx & 7, cg = cs ^ (r & 7);
            async16(Kbase + (size_t)(t0 + r) * 64 + cg * 8, Ks + idx * 8);
            async16(Qbase + (size_t)r * Dv + t0 + cg * 8, Qs + idx * 8);
        }
        if (tid < 64) {
            ms[tid] = mIn[(size_t)bh * Tv + t0 + tid];
            zs[tid] = zIn[(size_t)bh * Tv + t0 + tid];
        }
        __syncthreads();

        short8 aK0 = frag64(Ks, w * 16 + c, q);
        short8 aK1 = frag64(Ks, w * 16 + c, 4 + q);
#pragma unroll
        for (int sf = 0; sf < 8; sf++) {
            short8 b0 = frag64(Vs, sf * 16 + c, q);
            short8 b1 = frag64(Vs, sf * 16 + c, 4 + q);
            f32x4 l = {0.f, 0.f, 0.f, 0.f};
            l = MFMA16(aK0, b0, l);
            l = MFMA16(aK1, b1, l);
            short4v p4;
#pragma unroll
            for (int r = 0; r < 4; r++) {
                const int tr = w * 16 + q * 4 + r;
                float p = __expf(l[r] * ts - ms[tr]) * zs[tr];
                p4[r] = f2bf(p);
            }
            *(short4v*)&Pt[(sf * 16 + c) * 72 + w * 16 + q * 4] = p4;
        }
        __syncthreads();

        short8 aQ0 = frag64(Qs, w * 16 + c, q);
        short8 aQ1 = frag64(Qs, w * 16 + c, 4 + q);
#pragma unroll
        for (int sf = 0; sf < 8; sf++) {
            short8 p0 = *(const short8*)&Pt[(sf * 16 + c) * 72 + q * 8];
            short8 p1 = *(const short8*)&Pt[(sf * 16 + c) * 72 + 32 + q * 8];
            acc[sf] = MFMA16(aQ0, p0, acc[sf]);
            acc[sf] = MFMA16(aQ1, p1, acc[sf]);
        }
    }

#pragma unroll
    for (int sf = 0; sf < 8; sf++) {
#pragma unroll
        for (int r = 0; r < 4; r++) {
            const int d = w * 16 + q * 4 + r;
            out[(size_t)(b * Tv + h * DHv + d) * Dv + s0 + sf * 16 + c] = acc[sf][r];
        }
    }
}

extern "C" void kernel_launch(void* const* d_in, const int* in_sizes, int n_in,
                              void* d_out, int out_size, void* d_ws, size_t ws_size,
                              hipStream_t stream) {
    const float* x    = (const float*)d_in[0];
    const float* Wq   = (const float*)d_in[1];
    const float* bq   = (const float*)d_in[2];
    const float* Wk   = (const float*)d_in[3];
    const float* bk   = (const float*)d_in[4];
    const float* Wv   = (const float*)d_in[5];
    const float* bv   = (const float*)d_in[6];
    const float* temp = (const float*)d_in[7];
    float* out = (float*)d_out;

    char* ws = (char*)d_ws;
    short* xb = (short*)(ws);                       // [0, 8M)
    short* Wt = (short*)(ws + ((size_t)8 << 20));   // [8M, 14M)
    short* Qb = (short*)(ws + ((size_t)14 << 20));  // [14M, 22M)
    short* Kt = (short*)(ws + ((size_t)22 << 20));  // [22M, 30M)
    short* Vt = (short*)(ws + ((size_t)30 << 20));  // [30M, 38M)
    float* mbuf = (float*)(ws + ((size_t)38 << 20));
    float* zbuf = mbuf + 65536;

    cast_x<<<4096, 256, 0, stream>>>(x, xb);
    w_cast_t<<<dim3(16, 16, 3), 256, 0, stream>>>(Wq, Wk, Wv, Wt);
    qkv_mfma<<<dim3(8, 32, 3), 256, 0, stream>>>(xb, Wt, bq, bk, bv, Qb, Kt, Vt);
    attn_stats<<<dim3(16, 16, 4), 256, 0, stream>>>(Kt, Vt, temp, mbuf, zbuf);
    attn_out<<<dim3(8, 16, 4), 256, 0, stream>>>(Qb, Kt, Vt, temp, mbuf, zbuf, out);
}